// Round 6
// baseline (223.789 us; speedup 1.0000x reference)
//
#include <hip/hip_runtime.h>
#include <math.h>

// ---------------------------------------------------------------------------
// GraphMultisetTransformer forward, MI355X round 6:
//   - CHUNK=32, LDS 48KB -> 3 blocks/CU (6 waves/SIMD)
//   - 2 barriers/block: wave h owns its head's K/V/P (same-wave LDS reuse)
//   - burst staging (8 float4 in flight before first use)
//   - partials accumulated via atomicAdd into 0.5MB buffer (memset per call)
// ---------------------------------------------------------------------------

typedef __bf16 bf16x8 __attribute__((ext_vector_type(8)));
typedef float  f32x4  __attribute__((ext_vector_type(4)));

namespace {
constexpr int kB   = 16;
constexpr int kN   = 4096;
constexpr int kC   = 256;
constexpr int kEV  = 64;
constexpr int kH   = 8;
constexpr int kDH  = 32;
constexpr int kNQ  = 30;
constexpr int kCH  = 32;            // chunk rows
constexpr float kScale = 0.625f;    // 1/(16*0.1)
}

__device__ __forceinline__ unsigned short f32_to_bf16(float f) {
  unsigned int u = __float_as_uint(f);
  unsigned int r = (u + 0x7FFFu + ((u >> 16) & 1u)) >> 16;
  return (unsigned short)r;
}
__device__ __forceinline__ unsigned int pack_bf16(float a, float b) {
  return (unsigned int)f32_to_bf16(a) | ((unsigned int)f32_to_bf16(b) << 16);
}
__device__ __forceinline__ f32x4 splat4(float v) {
  f32x4 r; r[0] = v; r[1] = v; r[2] = v; r[3] = v; return r;
}

// ---------------------------------------------------------------------------
// prep: blocks [0,192) convert 6 W matrices f32->bf16; [192,704) Q projection
// ---------------------------------------------------------------------------
__global__ __launch_bounds__(256) void prep_kernel(
    const float* __restrict__ ev,
    const float* __restrict__ WqG, const float* __restrict__ WqD,
    const float* __restrict__ WqL,
    const float* __restrict__ WkG, const float* __restrict__ WkD,
    const float* __restrict__ WkL,
    const float* __restrict__ WvG, const float* __restrict__ WvD,
    const float* __restrict__ WvL,
    unsigned short* __restrict__ Wb,
    float* __restrict__ Qw, unsigned short* __restrict__ Qb)
{
  const int bid = blockIdx.x, tid = threadIdx.x;
  __shared__ float e[kEV];
  if (bid < 192) {
    const int mat = bid >> 5;
    const float* src = (mat == 0) ? WkG : (mat == 1) ? WkD : (mat == 2) ? WkL
                     : (mat == 3) ? WvG : (mat == 4) ? WvD : WvL;
    const int i0 = (((bid & 31) << 8) + tid) * 8;
    const float4* s4 = (const float4*)(src + i0);
    float4 a = s4[0], b = s4[1];
    uint4 pack = make_uint4(pack_bf16(a.x, a.y), pack_bf16(a.z, a.w),
                            pack_bf16(b.x, b.y), pack_bf16(b.z, b.w));
    *(uint4*)(Wb + (size_t)mat * 65536 + i0) = pack;
  } else {
    const int idx = bid - 192;
    const int b = idx >> 5, qq = idx & 31;
    if (qq >= kNQ) { Qb[((size_t)(b * 32 + qq)) * kC + tid] = 0; return; }
    if (tid < kEV) e[tid] = ev[((size_t)(b * kNQ + qq)) * kEV + tid];
    __syncthreads();
    const float* W = (qq < 10) ? WqG : (qq < 20) ? WqD : WqL;
    const float4* wr = (const float4*)(W + (size_t)tid * kEV);
    const float4* er = (const float4*)e;
    float s = 0.0f;
#pragma unroll
    for (int j = 0; j < kEV / 4; ++j) {
      float4 w = wr[j], v = er[j];
      s = fmaf(v.x, w.x, s); s = fmaf(v.y, w.y, s);
      s = fmaf(v.z, w.z, s); s = fmaf(v.w, w.w, s);
    }
    Qw[((size_t)(b * kNQ + qq)) * kC + tid] = s;
    Qb[((size_t)(b * 32 + qq)) * kC + tid] = f32_to_bf16(s * kScale);
  }
}

// ---------------------------------------------------------------------------
// Projection (32 rows x 256 cols/block, wave owns 32 cols)
// ---------------------------------------------------------------------------
struct ProjAcc2 { f32x4 acc[2][2]; f32x4 accX[2]; };

template <bool HASB>
__device__ __forceinline__ void proj_mfma32(
    const unsigned short* Xl,                       // LDS [32][256] swizzled
    const unsigned short* __restrict__ W0, const unsigned short* __restrict__ W1,
    const float* __restrict__ bias0, const float* __restrict__ bias1,
    int rsplit, bool two, int wcol0, int lane, ProjAcc2& P)
{
  const int lg = lane >> 4, lr = lane & 15;
  const bool strad = two && (rsplit & 15);
  const int ms = rsplit >> 4;                       // 0 or 1

#pragma unroll
  for (int n = 0; n < 2; ++n) {
    float b0v = 0.0f, b1v = 0.0f;
    if constexpr (HASB) {
      b0v = bias0[wcol0 + n * 16 + lr];
      b1v = two ? bias1[wcol0 + n * 16 + lr] : b0v;
    }
#pragma unroll
    for (int m = 0; m < 2; ++m)
      P.acc[m][n] = splat4((m * 16 < rsplit) ? b0v : b1v);
    P.accX[n] = splat4(b1v);
  }

#pragma unroll
  for (int kt = 0; kt < 8; ++kt) {
    bf16x8 a[2];
#pragma unroll
    for (int m = 0; m < 2; ++m) {
      const int row = m * 16 + lr;
      const int c16 = (kt * 4 + lg) ^ (row & 7);
      a[m] = *reinterpret_cast<const bf16x8*>(Xl + row * kC + c16 * 8);
    }
    bf16x8 ams = (ms == 1) ? a[1] : a[0];
    const int k0 = kt * 32 + lg * 8;
#pragma unroll
    for (int n = 0; n < 2; ++n) {
      const int ct = wcol0 + n * 16 + lr;
      bf16x8 b0 = *reinterpret_cast<const bf16x8*>(W0 + (size_t)ct * kC + k0);
      if (!two) {
#pragma unroll
        for (int m = 0; m < 2; ++m)
          P.acc[m][n] = __builtin_amdgcn_mfma_f32_16x16x32_bf16(a[m], b0, P.acc[m][n], 0, 0, 0);
      } else {
        bf16x8 b1 = *reinterpret_cast<const bf16x8*>(W1 + (size_t)ct * kC + k0);
#pragma unroll
        for (int m = 0; m < 2; ++m) {
          bf16x8 bs = (m * 16 < rsplit) ? b0 : b1;
          P.acc[m][n] = __builtin_amdgcn_mfma_f32_16x16x32_bf16(a[m], bs, P.acc[m][n], 0, 0, 0);
        }
        if (strad)
          P.accX[n] = __builtin_amdgcn_mfma_f32_16x16x32_bf16(ams, b1, P.accX[n], 0, 0, 0);
      }
    }
  }
}

__device__ __forceinline__ float sel_strad(const ProjAcc2& P, int m, int n, int j,
                                           int row, int rsplit, bool strad, int ms) {
  float v = P.acc[m][n][j];
  if (strad && m == ms && row >= rsplit) v = P.accX[n][j];
  return v;
}

// K layout: Kl[row][col ^ ((row&7)<<3)], rows = keys (32), cols = 256
__device__ __forceinline__ void store_K(
    unsigned short* Kl, const ProjAcc2& P,
    int rsplit, bool two, int wcol0, int lane)
{
  const int lg = lane >> 4, lr = lane & 15;
  const bool strad = two && (rsplit & 15);
  const int ms = rsplit >> 4;
#pragma unroll
  for (int m = 0; m < 2; ++m)
#pragma unroll
    for (int n = 0; n < 2; ++n) {
      const int col = wcol0 + n * 16 + lr;
#pragma unroll
      for (int j = 0; j < 4; ++j) {
        const int row = m * 16 + lg * 4 + j;
        Kl[row * kC + (col ^ ((row & 7) << 3))] =
            f32_to_bf16(sel_strad(P, m, n, j, row, rsplit, strad, ms));
      }
    }
}

// Vt layout: [col][key], 32 keys (64B) per col in 4 16B chunks, chunk ^= col&3
__device__ __forceinline__ void store_Vt(
    unsigned short* Vt, const ProjAcc2& P,
    int rsplit, bool two, int wcol0, int lane)
{
  const int lg = lane >> 4, lr = lane & 15;
  const bool strad = two && (rsplit & 15);
  const int ms = rsplit >> 4;
#pragma unroll
  for (int m = 0; m < 2; ++m)
#pragma unroll
    for (int n = 0; n < 2; ++n) {
      const int col = wcol0 + n * 16 + lr;
      const int row0 = m * 16 + lg * 4;
      const int kc = row0 >> 3;                    // key chunk
      unsigned short us[4];
#pragma unroll
      for (int j = 0; j < 4; ++j)
        us[j] = f32_to_bf16(sel_strad(P, m, n, j, row0 + j, rsplit, strad, ms));
      uint2 pk = make_uint2((unsigned int)us[0] | ((unsigned int)us[1] << 16),
                            (unsigned int)us[2] | ((unsigned int)us[3] << 16));
      *(uint2*)(Vt + col * kCH + (kc ^ (col & 3)) * 8 + (row0 & 7)) = pk;
    }
}

// ---------------------------------------------------------------------------
// Chunk kernel: blocks [0,24) wd partials; [24,...) compacted live 32-row
// chunks. 512 thr, 48KB LDS -> 3 blocks/CU. Two barriers.
// ---------------------------------------------------------------------------
__global__ __launch_bounds__(512, 6) void chunk_kernel(
    const float* __restrict__ x, const float* __restrict__ ox,
    const int* __restrict__ numv,
    const unsigned short* __restrict__ Wb,
    const float* __restrict__ bvG, const float* __restrict__ bvD,
    const float* __restrict__ bvL,
    const unsigned short* __restrict__ Qb,
    const float* __restrict__ Qw,
    float* __restrict__ PlA, float* __restrict__ PoA, float* __restrict__ wdp)
{
  __shared__ unsigned short Xs[kCH * kC];   // 16KB x tile (swizzled)
  __shared__ unsigned short Ov[kCH * kC];   // 16KB ox tile, then Vt
  __shared__ unsigned short Kl[kCH * kC];   // 16KB K (P aliased in own slots)

  const int tid = threadIdx.x;

  // ---- wd partial blocks ----
  if (blockIdx.x < 24) {
    const int g = blockIdx.x >> 3;
    const int h = blockIdx.x & 7;
    const int lo = g * 10;
    float* sred = (float*)Kl;
    float local = 0.0f;
    for (int b = 0; b < kB; ++b) {
      float v = 0.0f;
      if (tid < 100) {
        int i = tid / 10, j = tid % 10;
        const float* qi = Qw + ((size_t)(b * kNQ + lo + i)) * kC + h * kDH;
        const float* qj = Qw + ((size_t)(b * kNQ + lo + j)) * kC + h * kDH;
        float corr = 0.0f;
#pragma unroll
        for (int k = 0; k < kDH; ++k) corr = fmaf(qi[k], qj[k], corr);
        float diff = corr - (i == j ? 1.0f : 0.0f);
        v = diff * diff;
      }
      sred[tid] = v;
      __syncthreads();
      for (int s2 = 256; s2 > 0; s2 >>= 1) {
        if (tid < s2) sred[tid] += sred[tid + s2];
        __syncthreads();
      }
      if (tid == 0) local += sqrtf(sred[0]);
      __syncthreads();
    }
    if (tid == 0) wdp[blockIdx.x] = local * (1.0f / 16.0f);
    return;
  }

  // ---- live-chunk compaction (32-row chunks) ----
  int nv[17];
#pragma unroll
  for (int i = 0; i < 17; ++i) nv[i] = numv[i];
  int t = blockIdx.x - 24, b = 0, ch = -1;
#pragma unroll
  for (int bb = 0; bb < kB; ++bb) {
    const int lc = (3 * (nv[bb + 1] - nv[bb]) + 31) >> 5;
    if (ch < 0) { if (t < lc) { b = bb; ch = t; } else t -= lc; }
  }
  if (ch < 0) return;

  const int n0 = ch * kCH;
  const int d = nv[b + 1] - nv[b];
  const int limit = 3 * d;
  const int nvalid = min(kCH, limit - n0);

  const int lane = tid & 63, wv = tid >> 6;
  const int lg = lane >> 4, lr = lane & 15;
  const int wcol0 = wv * 32;

  // group structure: at most one boundary inside a 32-row chunk (d >= 64)
  const int g0 = (n0 >= 2 * d) ? 2 : (n0 >= d) ? 1 : 0;
  const int nL = n0 + kCH - 1;
  const int g1 = (nL >= 2 * d) ? 2 : (nL >= d) ? 1 : 0;
  const bool two = (g1 != g0);
  const int rsplit = two ? ((g1 == 1 ? d : 2 * d) - n0) : kCH;

  const unsigned short* WkA = Wb + (size_t)g0 * 65536;
  const unsigned short* WkB = Wb + (size_t)g1 * 65536;
  const unsigned short* WvA = Wb + (size_t)(3 + g0) * 65536;
  const unsigned short* WvB = Wb + (size_t)(3 + g1) * 65536;
  const float* bvA = (g0 == 0) ? bvG : (g0 == 1) ? bvD : bvL;
  const float* bvB = (g1 == 0) ? bvG : (g1 == 1) ? bvD : bvL;

  // ---- burst staging: 8 float4 loads in flight, then cvt + swizzled write --
  {
    const float4* xsrc = (const float4*)(x + ((size_t)b * kN + n0) * kC);
    const float4* osrc = (const float4*)(ox + ((size_t)b * kN + n0) * kC);
    float4 xa[4], oa[4];
    int rw[4], c4[4];
#pragma unroll
    for (int i = 0; i < 4; ++i) {
      const int cid = tid + i * 512;         // 0..2047 float4 slots
      rw[i] = cid >> 6; c4[i] = cid & 63;
      xa[i] = xsrc[(size_t)rw[i] * 64 + c4[i]];
    }
#pragma unroll
    for (int i = 0; i < 4; ++i) oa[i] = osrc[(size_t)rw[i] * 64 + c4[i]];
#pragma unroll
    for (int i = 0; i < 4; ++i) {
      const int row = rw[i], cc = c4[i];
      const int c16 = cc >> 1, half = (cc & 1) * 4;
      const int base = row * kC + ((c16 ^ (row & 7)) * 8) + half;
      *(uint2*)(Xs + base) = make_uint2(pack_bf16(xa[i].x, xa[i].y),
                                        pack_bf16(xa[i].z, xa[i].w));
      *(uint2*)(Ov + base) = make_uint2(pack_bf16(oa[i].x, oa[i].y),
                                        pack_bf16(oa[i].z, oa[i].w));
    }
  }
  __syncthreads();                                      // B1: tiles staged

  // ---- K projection -> Kl (own cols) ----
  {
    ProjAcc2 PK;
    proj_mfma32<false>(Xs, WkA, WkB, nullptr, nullptr, rsplit, two, wcol0, lane, PK);
    store_K(Kl, PK, rsplit, two, wcol0, lane);
  }

  // ---- V projection (acc in regs across B2) ----
  ProjAcc2 PV;
  proj_mfma32<true>(Ov, WvA, WvB, bvA, bvB, rsplit, two, wcol0, lane, PV);
  __syncthreads();                                      // B2: Ov reads done
  unsigned short* Vt = Ov;                              // alias
  store_Vt(Vt, PV, rsplit, two, wcol0, lane);

  // ---- attention: wave = head h (all LDS same-wave from here) ----
  const int h = wv;
  bf16x8 aq[2];
#pragma unroll
  for (int m = 0; m < 2; ++m)
    aq[m] = *reinterpret_cast<const bf16x8*>(
        Qb + ((size_t)(b * 32) + m * 16 + lr) * kC + h * kDH + lg * 8);

  f32x4 s[2][2];
#pragma unroll
  for (int m = 0; m < 2; ++m)
#pragma unroll
    for (int n = 0; n < 2; ++n) s[m][n] = splat4(0.0f);

#pragma unroll
  for (int n = 0; n < 2; ++n) {
    const int row = n * 16 + lr;                        // key
    const int c16 = (h * 4 + lg) ^ (row & 7);
    bf16x8 bk = *reinterpret_cast<const bf16x8*>(Kl + row * kC + c16 * 8);
    s[0][n] = __builtin_amdgcn_mfma_f32_16x16x32_bf16(aq[0], bk, s[0][n], 0, 0, 0);
    s[1][n] = __builtin_amdgcn_mfma_f32_16x16x32_bf16(aq[1], bk, s[1][n], 0, 0, 0);
  }

  // exp, P -> own Kl slots, lsum
  f32x4 lsum[2];
  lsum[0] = splat4(0.0f); lsum[1] = splat4(0.0f);
#pragma unroll
  for (int m = 0; m < 2; ++m)
#pragma unroll
    for (int n = 0; n < 2; ++n) {
      const int key = n * 16 + lr;
      const bool kok = key < nvalid;
      const int kc = n * 2 + (lr >> 3);
      f32x4 p;
#pragma unroll
      for (int j = 0; j < 4; ++j) p[j] = kok ? __expf(s[m][n][j]) : 0.0f;
      lsum[m] += p;
#pragma unroll
      for (int j = 0; j < 4; ++j) {
        const int q = m * 16 + lg * 4 + j;
        Kl[q * kC + ((4 * h + kc) ^ (q & 7)) * 8 + (key & 7)] = f32_to_bf16(p[j]);
      }
    }
#pragma unroll
  for (int msk = 1; msk < 16; msk <<= 1) {
#pragma unroll
    for (int m = 0; m < 2; ++m)
#pragma unroll
      for (int j = 0; j < 4; ++j)
        lsum[m][j] += __shfl_xor(lsum[m][j], msk, 16);
  }
  if (lr == 0) {
#pragma unroll
    for (int m = 0; m < 2; ++m)
#pragma unroll
      for (int j = 0; j < 4; ++j) {
        const int q = m * 16 + lg * 4 + j;
        if (q < kNQ) atomicAdd(&PlA[((size_t)(b * kNQ + q)) * kH + h], lsum[m][j]);
      }
  }

  // PV: A = P (own slots), B = Vt (own cols); contraction = 32 keys = 1 step
  f32x4 o[2][2];
#pragma unroll
  for (int m = 0; m < 2; ++m)
#pragma unroll
    for (int n = 0; n < 2; ++n) o[m][n] = splat4(0.0f);

  bf16x8 ap[2];
#pragma unroll
  for (int m = 0; m < 2; ++m) {
    const int q = m * 16 + lr;
    ap[m] = *reinterpret_cast<const bf16x8*>(Kl + q * kC + ((4 * h + lg) ^ (q & 7)) * 8);
  }
#pragma unroll
  for (int n = 0; n < 2; ++n) {
    const int col = h * kDH + n * 16 + lr;
    bf16x8 bv = *reinterpret_cast<const bf16x8*>(Vt + col * kCH + (lg ^ (col & 3)) * 8);
    o[0][n] = __builtin_amdgcn_mfma_f32_16x16x32_bf16(ap[0], bv, o[0][n], 0, 0, 0);
    o[1][n] = __builtin_amdgcn_mfma_f32_16x16x32_bf16(ap[1], bv, o[1][n], 0, 0, 0);
  }

#pragma unroll
  for (int m = 0; m < 2; ++m)
#pragma unroll
    for (int n = 0; n < 2; ++n)
#pragma unroll
      for (int j = 0; j < 4; ++j) {
        const int q = m * 16 + lg * 4 + j;
        if (q < kNQ)
          atomicAdd(&PoA[(((size_t)(b * kNQ + q)) * kH + h) * kDH + n * 16 + lr],
                    o[m][n][j]);
      }
}

// ---------------------------------------------------------------------------
// Combine: block [0,480) = (b,q) divide + epilogue; block 480 = wd total
// ---------------------------------------------------------------------------
__global__ __launch_bounds__(256) void combine_kernel(
    const float* __restrict__ PlA, const float* __restrict__ PoA,
    const float* __restrict__ Wo, const float* __restrict__ bo,
    const float* __restrict__ wdp,
    float* __restrict__ out)
{
  const int bq = blockIdx.x;
  const int tid = threadIdx.x;

  if (bq == kB * kNQ) {     // wd finalize
    float v = (tid < 24) ? wdp[tid] : 0.0f;
#pragma unroll
    for (int off = 32; off > 0; off >>= 1) v += __shfl_down(v, off);
    if (tid == 0) out[(size_t)kB * kNQ * kC] = v;
    return;
  }

  const int h = tid >> 5, kk = tid & 31;
  const float l = PlA[(size_t)bq * kH + h];
  const float attn = PoA[((size_t)bq * kH + h) * kDH + kk] / l;

  __shared__ float row[kC];
  row[tid] = attn;
  __syncthreads();

  const float4* wr = (const float4*)(Wo + (size_t)tid * kC);
  const float4* rr = (const float4*)row;
  float s = 0.0f;
#pragma unroll
  for (int j = 0; j < kC / 4; ++j) {
    float4 w = wr[j], v = rr[j];
    s = fmaf(v.x, w.x, s); s = fmaf(v.y, w.y, s);
    s = fmaf(v.z, w.z, s); s = fmaf(v.w, w.w, s);
  }
  s += bo[tid];
  const float y = attn + fmaxf(s, 0.0f);

  float v = y * y;
#pragma unroll
  for (int off = 32; off > 0; off >>= 1) v += __shfl_down(v, off);
  __shared__ float red[4];
  if ((tid & 63) == 0) red[tid >> 6] = v;
  __syncthreads();
  const float tot = red[0] + red[1] + red[2] + red[3];
  const float nrm = fmaxf(sqrtf(tot), 1e-12f);
  out[(size_t)bq * kC + tid] = y / nrm;
}

// ---------------------------------------------------------------------------
extern "C" void kernel_launch(void* const* d_in, const int* in_sizes, int n_in,
                              void* d_out, int out_size, void* d_ws, size_t ws_size,
                              hipStream_t stream) {
  const float* x    = (const float*)d_in[0];
  const float* ox   = (const float*)d_in[1];
  const float* ev   = (const float*)d_in[2];
  // d_in[3] = mask_cross: recomputed from numv, unused
  const int*   numv = (const int*)d_in[4];
  const float* WqG  = (const float*)d_in[5];
  const float* WqD  = (const float*)d_in[6];
  const float* WqL  = (const float*)d_in[7];
  const float* WkG  = (const float*)d_in[8];
  const float* WkD  = (const float*)d_in[9];
  const float* WkL  = (const float*)d_in[10];
  const float* WvG  = (const float*)d_in[11];
  const float* bvG  = (const float*)d_in[12];
  const float* WvD  = (const float*)d_in[13];
  const float* bvD  = (const float*)d_in[14];
  const float* WvL  = (const float*)d_in[15];
  const float* bvL  = (const float*)d_in[16];
  const float* Wo   = (const float*)d_in[17];
  const float* bo   = (const float*)d_in[18];

  float* out = (float*)d_out;
  char*  ws  = (char*)d_ws;

  // workspace layout (bytes)
  float* Qw = (float*)ws;                                        // 491,520
  unsigned short* Qb = (unsigned short*)(ws + 491520);           // 262,144
  unsigned short* Wb = (unsigned short*)(ws + 491520 + 262144);  // 786,432
  float* PlA = (float*)(ws + 1540096);                           // 15,360
  float* PoA = (float*)(ws + 1540096 + 15360);                   // 491,520
  float* wdp = (float*)(ws + 1540096 + 15360 + 491520);          // 96

  hipMemsetAsync(PlA, 0, 15360 + 491520, stream);
  prep_kernel<<<704, 256, 0, stream>>>(ev, WqG, WqD, WqL,
                                       WkG, WkD, WkL, WvG, WvD, WvL,
                                       Wb, Qw, Qb);
  chunk_kernel<<<24 + kB * (kN / kCH), 512, 0, stream>>>(
      x, ox, numv, Wb, bvG, bvD, bvL, Qb, Qw, PlA, PoA, wdp);
  combine_kernel<<<kB * kNQ + 1, 256, 0, stream>>>(PlA, PoA, Wo, bo, wdp, out);
}

// Round 7
// 155.909 us; speedup vs baseline: 1.4354x; 1.4354x over previous
//
#include <hip/hip_runtime.h>
#include <math.h>

// ---------------------------------------------------------------------------
// GraphMultisetTransformer forward, MI355X round 7:
//   - QK^T folded into projection: S = X @ Wqk^T, Wqk = (Q*scale) @ Wk  (per b,g,h)
//   - single-group chunks (per (b,g) segment, padded to 64) -> no straddle path
//   - T14: all x/ox loads issued at block start; 2 barriers per block
//   - K never materialized; P/Vt stored to LDS for same-wave reads only
//   - XCD-chunked swizzle so same-(b,g) blocks share L2 (Wqk locality)
// ---------------------------------------------------------------------------

typedef __bf16 bf16x8 __attribute__((ext_vector_type(8)));
typedef float  f32x4  __attribute__((ext_vector_type(4)));

namespace {
constexpr int kB   = 16;
constexpr int kN   = 4096;
constexpr int kC   = 256;
constexpr int kEV  = 64;
constexpr int kH   = 8;
constexpr int kDH  = 32;
constexpr int kNQ  = 30;
constexpr int kCH  = 64;            // chunk rows
constexpr int kMaxCB = 22;          // ceil(1366/64)
constexpr int kMaxT  = kB * 3 * kMaxCB;   // 1056 = 8*132 (divisible by 8)
constexpr float kScale = 0.625f;    // 1/(16*0.1)
}

__device__ __forceinline__ unsigned short f32_to_bf16(float f) {
  unsigned int u = __float_as_uint(f);
  unsigned int r = (u + 0x7FFFu + ((u >> 16) & 1u)) >> 16;
  return (unsigned short)r;
}
__device__ __forceinline__ unsigned int pack_bf16(float a, float b) {
  return (unsigned int)f32_to_bf16(a) | ((unsigned int)f32_to_bf16(b) << 16);
}
__device__ __forceinline__ f32x4 splat4(float v) {
  f32x4 r; r[0] = v; r[1] = v; r[2] = v; r[3] = v; return r;
}

// ---------------------------------------------------------------------------
// prep: blocks [0,96) convert 3 Wv matrices f32->bf16; [96,608) Q projection
// ---------------------------------------------------------------------------
__global__ __launch_bounds__(256) void prep_kernel(
    const float* __restrict__ ev,
    const float* __restrict__ WqG, const float* __restrict__ WqD,
    const float* __restrict__ WqL,
    const float* __restrict__ WvG, const float* __restrict__ WvD,
    const float* __restrict__ WvL,
    unsigned short* __restrict__ Wb, float* __restrict__ Qw)
{
  const int bid = blockIdx.x, tid = threadIdx.x;
  __shared__ float e[kEV];
  if (bid < 96) {
    const int mat = bid >> 5;
    const float* src = (mat == 0) ? WvG : (mat == 1) ? WvD : WvL;
    const int i0 = (((bid & 31) << 8) + tid) * 8;
    const float4* s4 = (const float4*)(src + i0);
    float4 a = s4[0], b = s4[1];
    uint4 pack = make_uint4(pack_bf16(a.x, a.y), pack_bf16(a.z, a.w),
                            pack_bf16(b.x, b.y), pack_bf16(b.z, b.w));
    *(uint4*)(Wb + (size_t)mat * 65536 + i0) = pack;
  } else {
    const int idx = bid - 96;
    const int b = idx >> 5, qq = idx & 31;
    if (qq >= kNQ) return;
    if (tid < kEV) e[tid] = ev[((size_t)(b * kNQ + qq)) * kEV + tid];
    __syncthreads();
    const float* W = (qq < 10) ? WqG : (qq < 20) ? WqD : WqL;
    const float4* wr = (const float4*)(W + (size_t)tid * kEV);
    const float4* er = (const float4*)e;
    float s = 0.0f;
#pragma unroll
    for (int j = 0; j < kEV / 4; ++j) {
      float4 w = wr[j], v = er[j];
      s = fmaf(v.x, w.x, s); s = fmaf(v.y, w.y, s);
      s = fmaf(v.z, w.z, s); s = fmaf(v.w, w.w, s);
    }
    Qw[((size_t)(b * kNQ + qq)) * kC + tid] = s;
  }
}

// ---------------------------------------------------------------------------
// wqk: Wqk[b,g,h][q 32][k 256] = scale * sum_c Q[b,q,h*32+c] * Wk_g[h*32+c,k]
// grid 384 = b*24 + g*8 + h, 256 threads; rows q>=30 are zero.
// ---------------------------------------------------------------------------
__global__ __launch_bounds__(256) void wqk_kernel(
    const float* __restrict__ Qw,
    const float* __restrict__ WkG, const float* __restrict__ WkD,
    const float* __restrict__ WkL,
    unsigned short* __restrict__ Wqkb)
{
  const int bid = blockIdx.x, tid = threadIdx.x;
  const int b = bid / 24, r = bid % 24, g = r >> 3, h = r & 7;
  const float* Wk = (g == 0) ? WkG : (g == 1) ? WkD : WkL;
  __shared__ float Qs[32][32];
#pragma unroll
  for (int i = 0; i < 4; ++i) {
    const int cid = tid + i * 256;
    const int q = cid >> 5, c = cid & 31;
    Qs[q][c] = (q < kNQ)
        ? Qw[((size_t)(b * kNQ + q)) * kC + h * 32 + c] * kScale : 0.0f;
  }
  __syncthreads();
  const int q = tid >> 3, kb = tid & 7;
  float acc[32];
#pragma unroll
  for (int j = 0; j < 32; ++j) acc[j] = 0.0f;
#pragma unroll 4
  for (int c = 0; c < 32; ++c) {
    const float qc = Qs[q][c];
    const float4* wr = (const float4*)(Wk + (size_t)(h * 32 + c) * kC + kb * 32);
#pragma unroll
    for (int j4 = 0; j4 < 8; ++j4) {
      float4 w = wr[j4];
      acc[j4 * 4 + 0] = fmaf(qc, w.x, acc[j4 * 4 + 0]);
      acc[j4 * 4 + 1] = fmaf(qc, w.y, acc[j4 * 4 + 1]);
      acc[j4 * 4 + 2] = fmaf(qc, w.z, acc[j4 * 4 + 2]);
      acc[j4 * 4 + 3] = fmaf(qc, w.w, acc[j4 * 4 + 3]);
    }
  }
  unsigned short* dst = Wqkb + ((size_t)bid * 32 + q) * kC + kb * 32;
#pragma unroll
  for (int j2 = 0; j2 < 16; ++j2)
    *(unsigned int*)(dst + j2 * 2) = pack_bf16(acc[2 * j2], acc[2 * j2 + 1]);
}

// ---------------------------------------------------------------------------
// Chunk kernel: blocks [0,24) wd partials; [24, 24+kMaxT) = (b,g,ch) chunks.
// 512 thr, 64KB LDS -> 2 blocks/CU. 2 barriers.
// ---------------------------------------------------------------------------
__global__ __launch_bounds__(512, 4) void chunk_kernel(
    const float* __restrict__ x, const float* __restrict__ ox,
    const int* __restrict__ numv,
    const unsigned short* __restrict__ Wb,      // 3 Wv matrices bf16
    const float* __restrict__ bvG, const float* __restrict__ bvD,
    const float* __restrict__ bvL,
    const unsigned short* __restrict__ Wqkb,    // [b,g,h][32][256] bf16
    const float* __restrict__ Qw,
    float* __restrict__ Pl, float* __restrict__ Po, float* __restrict__ wdp)
{
  __shared__ unsigned short Xs[kCH * kC];   // x staging -> P (8 x 4KB wave slots)
  __shared__ unsigned short Ov[kCH * kC];   // ox staging -> Vt

  const int tid = threadIdx.x;

  // ---- wd partial blocks ----
  if (blockIdx.x < 24) {
    const int g = blockIdx.x >> 3;
    const int h = blockIdx.x & 7;
    const int lo = g * 10;
    float* sred = (float*)Xs;
    float local = 0.0f;
    for (int b = 0; b < kB; ++b) {
      float v = 0.0f;
      if (tid < 100) {
        int i = tid / 10, j = tid % 10;
        const float* qi = Qw + ((size_t)(b * kNQ + lo + i)) * kC + h * kDH;
        const float* qj = Qw + ((size_t)(b * kNQ + lo + j)) * kC + h * kDH;
        float corr = 0.0f;
#pragma unroll
        for (int k = 0; k < kDH; ++k) corr = fmaf(qi[k], qj[k], corr);
        float diff = corr - (i == j ? 1.0f : 0.0f);
        v = diff * diff;
      }
      sred[tid] = v;
      __syncthreads();
      for (int s2 = 256; s2 > 0; s2 >>= 1) {
        if (tid < s2) sred[tid] += sred[tid + s2];
        __syncthreads();
      }
      if (tid == 0) local += sqrtf(sred[0]);
      __syncthreads();
    }
    if (tid == 0) wdp[blockIdx.x] = local * (1.0f / 16.0f);
    return;
  }

  // ---- XCD-chunked swizzle + (b,g,ch) decode ----
  int nv[17];
#pragma unroll
  for (int i = 0; i < 17; ++i) nv[i] = numv[i];
  const int p = blockIdx.x - 24;
  const int tt = (p & 7) * (kMaxT / 8) + (p >> 3);   // logical chunk id
  int rem = tt, b = -1, g = 0, ch = 0;
#pragma unroll
  for (int bb = 0; bb < kB; ++bb) {
    const int cb = (nv[bb + 1] - nv[bb] + 63) >> 6;
#pragma unroll
    for (int gg = 0; gg < 3; ++gg) {
      if (b < 0) { if (rem < cb) { b = bb; g = gg; ch = rem; } else rem -= cb; }
    }
  }
  if (b < 0) return;

  const int d = nv[b + 1] - nv[b];
  const int row0 = g * d + ch * kCH;                 // global row of key 0
  const int nvalid = min(min(kCH, d - ch * kCH), kN - row0);

  const int lane = tid & 63, wv = tid >> 6;
  const int lg = lane >> 4, lr = lane & 15;
  const int wcol0 = wv * 32;
  const int h = wv;                                  // wave = head

  const unsigned short* Wv_g = Wb + (size_t)g * 65536;
  const float* bv = (g == 0) ? bvG : (g == 1) ? bvD : bvL;
  const unsigned short* Wqk_h =
      Wqkb + ((size_t)((b * 3 + g) * 8 + h)) * 32 * kC;

  // ---- T14 staging: issue ALL x/ox loads up front ----
  const float* xb = x + (size_t)b * kN * kC;
  const float* ob = ox + (size_t)b * kN * kC;
  float4 xa[8], oa[8];
  int off[4];
#pragma unroll
  for (int i = 0; i < 4; ++i) {
    const int cid = tid + i * 512;                   // 16B-dst chunk id
    const int row = cid >> 5, c5 = cid & 31;
    const int rg = min(row0 + row, kN - 1);          // clamp (masked anyway)
    off[i] = rg * kC + c5 * 8;
    const float4* sx = (const float4*)(xb + off[i]);
    xa[2 * i] = sx[0]; xa[2 * i + 1] = sx[1];
  }
#pragma unroll
  for (int i = 0; i < 4; ++i) {
    const float4* so = (const float4*)(ob + off[i]);
    oa[2 * i] = so[0]; oa[2 * i + 1] = so[1];
  }
#pragma unroll
  for (int i = 0; i < 4; ++i) {
    const int cid = tid + i * 512;
    const int row = cid >> 5, c5 = cid & 31;
    const int base = row * kC + ((c5 ^ (row & 7)) * 8);
    *(uint4*)(Xs + base) = make_uint4(
        pack_bf16(xa[2 * i].x, xa[2 * i].y), pack_bf16(xa[2 * i].z, xa[2 * i].w),
        pack_bf16(xa[2 * i + 1].x, xa[2 * i + 1].y),
        pack_bf16(xa[2 * i + 1].z, xa[2 * i + 1].w));
    *(uint4*)(Ov + base) = make_uint4(
        pack_bf16(oa[2 * i].x, oa[2 * i].y), pack_bf16(oa[2 * i].z, oa[2 * i].w),
        pack_bf16(oa[2 * i + 1].x, oa[2 * i + 1].y),
        pack_bf16(oa[2 * i + 1].z, oa[2 * i + 1].w));
  }
  __syncthreads();                                   // B1: tiles staged

  // ---- S-projection: S[key 64][q 32] = X @ Wqk_h^T ----
  f32x4 s[4][2];
#pragma unroll
  for (int m = 0; m < 4; ++m)
#pragma unroll
    for (int n = 0; n < 2; ++n) s[m][n] = splat4(0.0f);

#pragma unroll
  for (int kt = 0; kt < 8; ++kt) {
    bf16x8 a[4];
#pragma unroll
    for (int m = 0; m < 4; ++m) {
      const int row = m * 16 + lr;
      const int c16 = (kt * 4 + lg) ^ (row & 7);
      a[m] = *reinterpret_cast<const bf16x8*>(Xs + row * kC + c16 * 8);
    }
    const int k0 = kt * 32 + lg * 8;
#pragma unroll
    for (int n = 0; n < 2; ++n) {
      bf16x8 bq = *reinterpret_cast<const bf16x8*>(
          Wqk_h + (size_t)(n * 16 + lr) * kC + k0);
#pragma unroll
      for (int m = 0; m < 4; ++m)
        s[m][n] = __builtin_amdgcn_mfma_f32_16x16x32_bf16(a[m], bq, s[m][n], 0, 0, 0);
    }
  }

  // ---- exp -> packed bf16 P in regs; row-sums ----
  unsigned int pp[4][2][2];
  f32x4 lsum[2];
  lsum[0] = splat4(0.0f); lsum[1] = splat4(0.0f);
#pragma unroll
  for (int m = 0; m < 4; ++m)
#pragma unroll
    for (int n = 0; n < 2; ++n) {
      f32x4 pv;
#pragma unroll
      for (int j = 0; j < 4; ++j) {
        const int key = m * 16 + lg * 4 + j;
        pv[j] = (key < nvalid) ? __expf(s[m][n][j]) : 0.0f;
      }
      lsum[n] += pv;
      pp[m][n][0] = pack_bf16(pv[0], pv[1]);
      pp[m][n][1] = pack_bf16(pv[2], pv[3]);
    }
  float ls[2];
#pragma unroll
  for (int n = 0; n < 2; ++n) {
    float v = (lsum[n][0] + lsum[n][1]) + (lsum[n][2] + lsum[n][3]);
    v += __shfl_xor(v, 16);
    v += __shfl_xor(v, 32);
    ls[n] = v;
  }
  if (lg == 0) {
#pragma unroll
    for (int n = 0; n < 2; ++n) {
      const int q = n * 16 + lr;
      if (q < kNQ) Pl[((size_t)tt * kNQ + q) * kH + h] = ls[n];
    }
  }

  // ---- V projection (acc in regs across B2) ----
  f32x4 vacc[4][2];
#pragma unroll
  for (int n = 0; n < 2; ++n) {
    const float bvv = bv[wcol0 + n * 16 + lr];
#pragma unroll
    for (int m = 0; m < 4; ++m) vacc[m][n] = splat4(bvv);
  }
#pragma unroll
  for (int kt = 0; kt < 8; ++kt) {
    bf16x8 a[4];
#pragma unroll
    for (int m = 0; m < 4; ++m) {
      const int row = m * 16 + lr;
      const int c16 = (kt * 4 + lg) ^ (row & 7);
      a[m] = *reinterpret_cast<const bf16x8*>(Ov + row * kC + c16 * 8);
    }
    const int k0 = kt * 32 + lg * 8;
#pragma unroll
    for (int n = 0; n < 2; ++n) {
      bf16x8 bw = *reinterpret_cast<const bf16x8*>(
          Wv_g + (size_t)(wcol0 + n * 16 + lr) * kC + k0);
#pragma unroll
      for (int m = 0; m < 4; ++m)
        vacc[m][n] = __builtin_amdgcn_mfma_f32_16x16x32_bf16(a[m], bw, vacc[m][n], 0, 0, 0);
    }
  }
  __syncthreads();                 // B2: all Xs/Ov reads done; safe to overwrite

  // ---- P -> own-wave Xs slot ----
  unsigned short* Pw = Xs + wv * 2048;       // [32 q][64 key] swizzled
#pragma unroll
  for (int m = 0; m < 4; ++m)
#pragma unroll
    for (int n = 0; n < 2; ++n) {
      const int q = n * 16 + lr;
      const int ckp = (2 * m + (lg >> 1)) ^ (q & 7);
      unsigned short* pa = Pw + q * kCH + ckp * 8 + (lg & 1) * 4;
      *(unsigned int*)(pa) = pp[m][n][0];
      *(unsigned int*)(pa + 2) = pp[m][n][1];
    }

  // ---- Vt -> Ov space: [col][key] swizzled (own cols) ----
#pragma unroll
  for (int m = 0; m < 4; ++m)
#pragma unroll
    for (int n = 0; n < 2; ++n) {
      const int col = wcol0 + n * 16 + lr;
      const int r0 = m * 16 + lg * 4;
      unsigned short us[4];
#pragma unroll
      for (int j = 0; j < 4; ++j) us[j] = f32_to_bf16(vacc[m][n][j]);
      const int ck = (r0 >> 3) ^ (col & 7);
      *(uint2*)(Ov + col * kCH + ck * 8 + (r0 & 7)) =
          make_uint2((unsigned int)us[0] | ((unsigned int)us[1] << 16),
                     (unsigned int)us[2] | ((unsigned int)us[3] << 16));
    }

  // ---- PV: O[q][dh] = sum_key P[q][key] * V[key][dh]  (all same-wave LDS) --
  f32x4 o[2][2];
#pragma unroll
  for (int m = 0; m < 2; ++m)
#pragma unroll
    for (int n = 0; n < 2; ++n) o[m][n] = splat4(0.0f);

#pragma unroll
  for (int ks = 0; ks < 2; ++ks) {
    bf16x8 ap[2];
#pragma unroll
    for (int mq = 0; mq < 2; ++mq) {
      const int q = mq * 16 + lr;
      ap[mq] = *reinterpret_cast<const bf16x8*>(
          Pw + q * kCH + (((ks * 4 + lg) ^ (q & 7))) * 8);
    }
#pragma unroll
    for (int n = 0; n < 2; ++n) {
      const int col = wcol0 + n * 16 + lr;
      bf16x8 bvf = *reinterpret_cast<const bf16x8*>(
          Ov + col * kCH + (((ks * 4 + lg) ^ (col & 7))) * 8);
      o[0][n] = __builtin_amdgcn_mfma_f32_16x16x32_bf16(ap[0], bvf, o[0][n], 0, 0, 0);
      o[1][n] = __builtin_amdgcn_mfma_f32_16x16x32_bf16(ap[1], bvf, o[1][n], 0, 0, 0);
    }
  }

#pragma unroll
  for (int mq = 0; mq < 2; ++mq)
#pragma unroll
    for (int n = 0; n < 2; ++n)
#pragma unroll
      for (int j = 0; j < 4; ++j) {
        const int q = mq * 16 + lg * 4 + j;
        if (q < kNQ)
          Po[(((size_t)tt * kNQ + q) * kH + h) * kDH + n * 16 + lr] = o[mq][n][j];
      }
}

// ---------------------------------------------------------------------------
// Combine: block [0,480) = (b,q) partial-sum + epilogue; block 480 = wd total
// ---------------------------------------------------------------------------
__global__ __launch_bounds__(256) void combine_kernel(
    const float* __restrict__ Pl, const float* __restrict__ Po,
    const int* __restrict__ numv,
    const float* __restrict__ Wo, const float* __restrict__ bo,
    const float* __restrict__ wdp,
    float* __restrict__ out)
{
  const int bq = blockIdx.x;
  const int tid = threadIdx.x;

  if (bq == kB * kNQ) {     // wd finalize
    float v = (tid < 24) ? wdp[tid] : 0.0f;
#pragma unroll
    for (int off = 32; off > 0; off >>= 1) v += __shfl_down(v, off);
    if (tid == 0) out[(size_t)kB * kNQ * kC] = v;
    return;
  }

  const int b = bq / kNQ, q = bq % kNQ;
  const int h = tid >> 5, kk = tid & 31;

  // chunk-id range for batch b
  int base = 0, cnt = 0, S = 0;
#pragma unroll
  for (int bb = 0; bb < kB; ++bb) {
    const int c3 = 3 * ((numv[bb + 1] - numv[bb] + 63) >> 6);
    if (bb == b) { base = S; cnt = c3; }
    S += c3;
  }

  float l = 0.0f, oacc = 0.0f;
#pragma unroll 4
  for (int i = 0; i < cnt; ++i) {
    const size_t idx = ((size_t)(base + i) * kNQ + q) * kH + h;
    l += Pl[idx];
    oacc += Po[idx * kDH + kk];
  }
  const float attn = oacc / l;

  __shared__ float row[kC];
  row[tid] = attn;
  __syncthreads();

  const float4* wr = (const float4*)(Wo + (size_t)tid * kC);
  const float4* rr = (const float4*)row;
  float s = 0.0f;
#pragma unroll
  for (int j = 0; j < kC / 4; ++j) {
    float4 w = wr[j], v = rr[j];
    s = fmaf(v.x, w.x, s); s = fmaf(v.y, w.y, s);
    s = fmaf(v.z, w.z, s); s = fmaf(v.w, w.w, s);
  }
  s += bo[tid];
  const float y = attn + fmaxf(s, 0.0f);

  float v = y * y;
#pragma unroll
  for (int off = 32; off > 0; off >>= 1) v += __shfl_down(v, off);
  __shared__ float red[4];
  if ((tid & 63) == 0) red[tid >> 6] = v;
  __syncthreads();
  const float tot = red[0] + red[1] + red[2] + red[3];
  const float nrm = fmaxf(sqrtf(tot), 1e-12f);
  out[(size_t)bq * kC + tid] = y / nrm;
}

// ---------------------------------------------------------------------------
extern "C" void kernel_launch(void* const* d_in, const int* in_sizes, int n_in,
                              void* d_out, int out_size, void* d_ws, size_t ws_size,
                              hipStream_t stream) {
  const float* x    = (const float*)d_in[0];
  const float* ox   = (const float*)d_in[1];
  const float* ev   = (const float*)d_in[2];
  // d_in[3] = mask_cross: recomputed from numv, unused
  const int*   numv = (const int*)d_in[4];
  const float* WqG  = (const float*)d_in[5];
  const float* WqD  = (const float*)d_in[6];
  const float* WqL  = (const float*)d_in[7];
  const float* WkG  = (const float*)d_in[8];
  const float* WkD  = (const float*)d_in[9];
  const float* WkL  = (const float*)d_in[10];
  const float* WvG  = (const float*)d_in[11];
  const float* bvG  = (const float*)d_in[12];
  const float* WvD  = (const float*)d_in[13];
  const float* bvD  = (const float*)d_in[14];
  const float* WvL  = (const float*)d_in[15];
  const float* bvL  = (const float*)d_in[16];
  const float* Wo   = (const float*)d_in[17];
  const float* bo   = (const float*)d_in[18];

  float* out = (float*)d_out;
  char*  ws  = (char*)d_ws;

  // workspace layout (bytes)
  size_t off = 0;
  float* Qw = (float*)(ws + off);            off += 491520;      // 16*30*256*4
  unsigned short* Wb = (unsigned short*)(ws + off); off += 393216;   // 3*256*256*2
  unsigned short* Wqkb = (unsigned short*)(ws + off); off += 6291456; // 384*32*256*2
  float* Pl  = (float*)(ws + off);           off += (size_t)kMaxT * kNQ * kH * 4;
  float* Po  = (float*)(ws + off);           off += (size_t)kMaxT * kNQ * kH * kDH * 4;
  float* wdp = (float*)(ws + off);           off += 96;

  prep_kernel<<<608, 256, 0, stream>>>(ev, WqG, WqD, WqL, WvG, WvD, WvL, Wb, Qw);
  wqk_kernel<<<384, 256, 0, stream>>>(Qw, WkG, WkD, WkL, Wqkb);
  chunk_kernel<<<24 + kMaxT, 512, 0, stream>>>(
      x, ox, numv, Wb, bvG, bvD, bvL, Wqkb, Qw, Pl, Po, wdp);
  combine_kernel<<<kB * kNQ + 1, 256, 0, stream>>>(Pl, Po, numv, Wo, bo, wdp, out);
}